// Round 1
// baseline (1406.990 us; speedup 1.0000x reference)
//
#include <hip/hip_runtime.h>

#define NN 100000
#define NE 1600000
#define DIMS 32

// workspace layout (in floats)
static constexpr long long OFF_HN  = 0;          // hn: NN*32 = 3.2M
static constexpr long long OFF_NUM = 3200000;    // num: 3.2M
static constexpr long long OFF_DEN = 6400000;    // den: 3.2M
static constexpr long long OFF_SE  = 9600000;    // stats_e: 32 copies * 64
static constexpr long long OFF_SH  = 9602048;    // stats_h: 32 copies * 64
static constexpr long long OFF_FIN = 9604096;    // finals: 128
static constexpr int SCOPIES = 32;

// ---------------- kernel A: hn = h * norm ----------------
__global__ __launch_bounds__(256) void k_hn(const float* __restrict__ h,
                                            const float* __restrict__ norm,
                                            float* __restrict__ hn) {
  int i = blockIdx.x * blockDim.x + threadIdx.x;   // slot over NN*8 float4s
  if (i >= NN * 8) return;
  float4 v = reinterpret_cast<const float4*>(h)[i];
  float nm = norm[i >> 3];
  v.x *= nm; v.y *= nm; v.z *= nm; v.w *= nm;
  reinterpret_cast<float4*>(hn)[i] = v;
}

// ---------------- kernel B: per-edge gate + scatter + e-stats ----------------
__global__ __launch_bounds__(256) void k_edge(const float* __restrict__ e,
                                              const float* __restrict__ hn,
                                              const int* __restrict__ src,
                                              const int* __restrict__ dst,
                                              float* __restrict__ num,
                                              float* __restrict__ den,
                                              float* __restrict__ eij,
                                              float* __restrict__ stats_e) {
  const int lane = threadIdx.x & 7;                 // 8 threads per edge
  const int slot0 = (blockIdx.x * blockDim.x + threadIdx.x) >> 3;
  const int nslots = (gridDim.x * blockDim.x) >> 3;
  float s0 = 0.f, s1 = 0.f, s2 = 0.f, s3 = 0.f;
  float q0 = 0.f, q1 = 0.f, q2 = 0.f, q3 = 0.f;

  for (int k = slot0; k < NE; k += nslots) {
    const int sidx = src[k];
    const int didx = dst[k];
    float4 ev = reinterpret_cast<const float4*>(e)[(long long)k * 8 + lane];
    float4 hs = reinterpret_cast<const float4*>(hn)[(long long)sidx * 8 + lane];
    float4 hd = reinterpret_cast<const float4*>(hn)[(long long)didx * 8 + lane];
    float x0 = ev.x + hs.x + hd.x;
    float x1 = ev.y + hs.y + hd.y;
    float x2 = ev.z + hs.z + hd.z;
    float x3 = ev.w + hs.w + hd.w;
    reinterpret_cast<float4*>(eij)[(long long)k * 8 + lane] = make_float4(x0, x1, x2, x3);
    float g0 = 1.f / (1.f + __expf(-x0));
    float g1 = 1.f / (1.f + __expf(-x1));
    float g2 = 1.f / (1.f + __expf(-x2));
    float g3 = 1.f / (1.f + __expf(-x3));
    float* nb = num + (long long)didx * DIMS + lane * 4;
    float* db = den + (long long)didx * DIMS + lane * 4;
    atomicAdd(nb + 0, g0 * hs.x);
    atomicAdd(nb + 1, g1 * hs.y);
    atomicAdd(nb + 2, g2 * hs.z);
    atomicAdd(nb + 3, g3 * hs.w);
    atomicAdd(db + 0, g0);
    atomicAdd(db + 1, g1);
    atomicAdd(db + 2, g2);
    atomicAdd(db + 3, g3);
    s0 += x0; s1 += x1; s2 += x2; s3 += x3;
    q0 += x0 * x0; q1 += x1 * x1; q2 += x2 * x2; q3 += x3 * x3;
  }

  __shared__ float sh[64];
  if (threadIdx.x < 64) sh[threadIdx.x] = 0.f;
  __syncthreads();
  const int cb = lane * 4;
  atomicAdd(&sh[cb + 0], s0); atomicAdd(&sh[cb + 1], s1);
  atomicAdd(&sh[cb + 2], s2); atomicAdd(&sh[cb + 3], s3);
  atomicAdd(&sh[32 + cb + 0], q0); atomicAdd(&sh[32 + cb + 1], q1);
  atomicAdd(&sh[32 + cb + 2], q2); atomicAdd(&sh[32 + cb + 3], q3);
  __syncthreads();
  if (threadIdx.x < 64)
    atomicAdd(&stats_e[(blockIdx.x & (SCOPIES - 1)) * 64 + threadIdx.x], sh[threadIdx.x]);
}

// ---------------- kernel C: node update + h-stats ----------------
__global__ __launch_bounds__(256) void k_node(const float* __restrict__ hn,
                                              const float* __restrict__ num,
                                              const float* __restrict__ den,
                                              const float* __restrict__ norm,
                                              float* __restrict__ hpre,
                                              float* __restrict__ stats_h) {
  const int i0 = blockIdx.x * blockDim.x + threadIdx.x;
  const int stride = gridDim.x * blockDim.x;   // multiple of 8 -> lane constant
  const int lane = threadIdx.x & 7;
  float s0 = 0.f, s1 = 0.f, s2 = 0.f, s3 = 0.f;
  float q0 = 0.f, q1 = 0.f, q2 = 0.f, q3 = 0.f;

  for (int i = i0; i < NN * 8; i += stride) {
    float4 hv = reinterpret_cast<const float4*>(hn)[i];
    float4 nu = reinterpret_cast<const float4*>(num)[i];
    float4 dn = reinterpret_cast<const float4*>(den)[i];
    float nm = norm[i >> 3];
    float x0 = (hv.x + nu.x / (dn.x + 1e-6f)) * nm;
    float x1 = (hv.y + nu.y / (dn.y + 1e-6f)) * nm;
    float x2 = (hv.z + nu.z / (dn.z + 1e-6f)) * nm;
    float x3 = (hv.w + nu.w / (dn.w + 1e-6f)) * nm;
    reinterpret_cast<float4*>(hpre)[i] = make_float4(x0, x1, x2, x3);
    s0 += x0; s1 += x1; s2 += x2; s3 += x3;
    q0 += x0 * x0; q1 += x1 * x1; q2 += x2 * x2; q3 += x3 * x3;
  }

  __shared__ float sh[64];
  if (threadIdx.x < 64) sh[threadIdx.x] = 0.f;
  __syncthreads();
  const int cb = lane * 4;
  atomicAdd(&sh[cb + 0], s0); atomicAdd(&sh[cb + 1], s1);
  atomicAdd(&sh[cb + 2], s2); atomicAdd(&sh[cb + 3], s3);
  atomicAdd(&sh[32 + cb + 0], q0); atomicAdd(&sh[32 + cb + 1], q1);
  atomicAdd(&sh[32 + cb + 2], q2); atomicAdd(&sh[32 + cb + 3], q3);
  __syncthreads();
  if (threadIdx.x < 64)
    atomicAdd(&stats_h[(blockIdx.x & (SCOPIES - 1)) * 64 + threadIdx.x], sh[threadIdx.x]);
}

// ---------------- kernel D: finalize BN statistics ----------------
__global__ void k_fin(const float* __restrict__ stats_e,
                      const float* __restrict__ stats_h,
                      float* __restrict__ fin) {
  int t = threadIdx.x;   // 64 threads
  if (t < 32) {
    float s = 0.f, q = 0.f;
    for (int c = 0; c < SCOPIES; ++c) {
      s += stats_h[c * 64 + t];
      q += stats_h[c * 64 + 32 + t];
    }
    float mean = s / (float)NN;
    float var = q / (float)NN - mean * mean;
    fin[t] = mean;
    fin[32 + t] = rsqrtf(var + 1e-5f);
  } else {
    int col = t - 32;
    float s = 0.f, q = 0.f;
    for (int c = 0; c < SCOPIES; ++c) {
      s += stats_e[c * 64 + col];
      q += stats_e[c * 64 + 32 + col];
    }
    float mean = s / (float)NE;
    float var = q / (float)NE - mean * mean;
    fin[64 + col] = mean;
    fin[96 + col] = rsqrtf(var + 1e-5f);
  }
}

// ---------------- kernel E/F: in-place BN + ReLU apply ----------------
__global__ __launch_bounds__(256) void k_apply(float* __restrict__ buf,
                                               long long nslots,
                                               const float* __restrict__ mean,
                                               const float* __restrict__ inv,
                                               const float* __restrict__ gamma,
                                               const float* __restrict__ beta) {
  long long i = (long long)blockIdx.x * blockDim.x + threadIdx.x;
  if (i >= nslots) return;
  const int cb = (int)(i & 7) * 4;
  float4 x = reinterpret_cast<float4*>(buf)[i];
  float y0 = fmaxf(0.f, (x.x - mean[cb + 0]) * inv[cb + 0] * gamma[cb + 0] + beta[cb + 0]);
  float y1 = fmaxf(0.f, (x.y - mean[cb + 1]) * inv[cb + 1] * gamma[cb + 1] + beta[cb + 1]);
  float y2 = fmaxf(0.f, (x.z - mean[cb + 2]) * inv[cb + 2] * gamma[cb + 2] + beta[cb + 2]);
  float y3 = fmaxf(0.f, (x.w - mean[cb + 3]) * inv[cb + 3] * gamma[cb + 3] + beta[cb + 3]);
  reinterpret_cast<float4*>(buf)[i] = make_float4(y0, y1, y2, y3);
}

extern "C" void kernel_launch(void* const* d_in, const int* in_sizes, int n_in,
                              void* d_out, int out_size, void* d_ws, size_t ws_size,
                              hipStream_t stream) {
  const float* h     = (const float*)d_in[0];
  const float* e     = (const float*)d_in[1];
  const float* norm  = (const float*)d_in[2];
  const int*   src   = (const int*)d_in[3];
  const int*   dst   = (const int*)d_in[4];
  const float* gh    = (const float*)d_in[5];
  const float* bh    = (const float*)d_in[6];
  const float* ge    = (const float*)d_in[7];
  const float* be    = (const float*)d_in[8];
  (void)in_sizes; (void)n_in; (void)out_size; (void)ws_size;

  float* ws  = (float*)d_ws;
  float* hn  = ws + OFF_HN;
  float* num = ws + OFF_NUM;
  float* den = ws + OFF_DEN;
  float* se  = ws + OFF_SE;
  float* shh = ws + OFF_SH;
  float* fin = ws + OFF_FIN;

  float* out  = (float*)d_out;
  float* hpre = out;                           // [NN*32] h output region
  float* eout = out + (long long)NN * DIMS;    // [NE*32] e output region

  // zero num, den, stats (contiguous region)
  hipMemsetAsync(num, 0, (size_t)(OFF_FIN - OFF_NUM) * sizeof(float), stream);

  k_hn<<<(NN * 8 + 255) / 256, 256, 0, stream>>>(h, norm, hn);
  k_edge<<<2048, 256, 0, stream>>>(e, hn, src, dst, num, den, eout, se);
  k_node<<<1024, 256, 0, stream>>>(hn, num, den, norm, hpre, shh);
  k_fin<<<1, 64, 0, stream>>>(se, shh, fin);
  k_apply<<<(NN * 8 + 255) / 256, 256, 0, stream>>>(hpre, (long long)NN * 8,
                                                    fin + 0, fin + 32, gh, bh);
  k_apply<<<((long long)NE * 8 + 255) / 256, 256, 0, stream>>>(eout, (long long)NE * 8,
                                                               fin + 64, fin + 96, ge, be);
}

// Round 2
// 666.638 us; speedup vs baseline: 2.1106x; 2.1106x over previous
//
#include <hip/hip_runtime.h>

#define NN 100000
#define NE 1600000
#define DIMS 32
static constexpr int SCOPIES = 32;

// workspace layout (float offsets)
static constexpr long long OFF_HN   = 0;          // 3.2M floats
static constexpr long long OFF_DEG  = 3200000;    // 100000 ints   [zeroed]
static constexpr long long OFF_SE   = 3300000;    // 2048 floats   [zeroed]
static constexpr long long OFF_SH   = 3302048;    // 2048 floats   [zeroed]
static constexpr long long OFF_FIN  = 3304096;    // 128 floats
static constexpr long long OFF_OFFS = 3304224;    // 100001 ints
static constexpr long long OFF_CURS = 3404232;    // 100000 ints
static constexpr long long OFF_EID  = 3504232;    // 1.6M ints

// ---------------- kernel A: hn = h * norm ----------------
__global__ __launch_bounds__(256) void k_hn(const float* __restrict__ h,
                                            const float* __restrict__ norm,
                                            float* __restrict__ hn) {
  int i = blockIdx.x * blockDim.x + threadIdx.x;   // float4 slots, NN*8
  if (i >= NN * 8) return;
  float4 v = reinterpret_cast<const float4*>(h)[i];
  float nm = norm[i >> 3];
  v.x *= nm; v.y *= nm; v.z *= nm; v.w *= nm;
  reinterpret_cast<float4*>(hn)[i] = v;
}

// ---------------- kernel B: e_ij compute + dst histogram + e-stats ----------------
__global__ __launch_bounds__(256) void k_edge(const float* __restrict__ e,
                                              const float* __restrict__ hn,
                                              const int* __restrict__ src,
                                              const int* __restrict__ dst,
                                              float* __restrict__ eij,
                                              int* __restrict__ deg,
                                              float* __restrict__ stats_e) {
  const int lane = threadIdx.x & 7;                 // 8 threads per edge
  const int slot0 = (blockIdx.x * blockDim.x + threadIdx.x) >> 3;
  const int nslots = (gridDim.x * blockDim.x) >> 3;
  float s0 = 0.f, s1 = 0.f, s2 = 0.f, s3 = 0.f;
  float q0 = 0.f, q1 = 0.f, q2 = 0.f, q3 = 0.f;

  for (int k = slot0; k < NE; k += nslots) {
    const int sidx = src[k];
    const int didx = dst[k];
    float4 ev = reinterpret_cast<const float4*>(e)[(long long)k * 8 + lane];
    float4 hs = reinterpret_cast<const float4*>(hn)[(long long)sidx * 8 + lane];
    float4 hd = reinterpret_cast<const float4*>(hn)[(long long)didx * 8 + lane];
    float x0 = ev.x + hs.x + hd.x;
    float x1 = ev.y + hs.y + hd.y;
    float x2 = ev.z + hs.z + hd.z;
    float x3 = ev.w + hs.w + hd.w;
    reinterpret_cast<float4*>(eij)[(long long)k * 8 + lane] = make_float4(x0, x1, x2, x3);
    if (lane == 0) atomicAdd(&deg[didx], 1);
    s0 += x0; s1 += x1; s2 += x2; s3 += x3;
    q0 += x0 * x0; q1 += x1 * x1; q2 += x2 * x2; q3 += x3 * x3;
  }

  __shared__ float sh[64];
  if (threadIdx.x < 64) sh[threadIdx.x] = 0.f;
  __syncthreads();
  const int cb = lane * 4;
  atomicAdd(&sh[cb + 0], s0); atomicAdd(&sh[cb + 1], s1);
  atomicAdd(&sh[cb + 2], s2); atomicAdd(&sh[cb + 3], s3);
  atomicAdd(&sh[32 + cb + 0], q0); atomicAdd(&sh[32 + cb + 1], q1);
  atomicAdd(&sh[32 + cb + 2], q2); atomicAdd(&sh[32 + cb + 3], q3);
  __syncthreads();
  if (threadIdx.x < 64)
    atomicAdd(&stats_e[(blockIdx.x & (SCOPIES - 1)) * 64 + threadIdx.x], sh[threadIdx.x]);
}

// ---------------- kernel C: exclusive scan of degrees (one block) ----------------
__global__ __launch_bounds__(1024) void k_scan(const int* __restrict__ deg,
                                               int* __restrict__ offs,
                                               int* __restrict__ curs) {
  __shared__ int part[1024];
  const int t = threadIdx.x;
  const int per = (NN + 1023) / 1024;     // 98
  const int lo = t * per;
  const int hi = (lo + per < NN) ? lo + per : NN;
  int s = 0;
  for (int i = lo; i < hi; ++i) s += deg[i];
  part[t] = s;
  __syncthreads();
  // Hillis-Steele inclusive scan
  for (int d = 1; d < 1024; d <<= 1) {
    int tmp = (t >= d) ? part[t - d] : 0;
    __syncthreads();
    part[t] += tmp;
    __syncthreads();
  }
  int run = part[t] - s;                  // exclusive prefix
  for (int i = lo; i < hi; ++i) {
    offs[i] = run;
    curs[i] = run;
    run += deg[i];
  }
  if (t == 1023) offs[NN] = run;          // == NE
}

// ---------------- kernel D: scatter edge ids into CSR ----------------
__global__ __launch_bounds__(256) void k_scatter(const int* __restrict__ dst,
                                                 int* __restrict__ curs,
                                                 int* __restrict__ eid) {
  int k = blockIdx.x * blockDim.x + threadIdx.x;
  if (k >= NE) return;
  int pos = atomicAdd(&curs[dst[k]], 1);
  eid[pos] = k;
}

// ---------------- kernel E: gather-aggregate + node update + h-stats ----------------
__global__ __launch_bounds__(256) void k_agg(const float* __restrict__ hn,
                                             const float* __restrict__ eij,
                                             const int* __restrict__ offs,
                                             const int* __restrict__ eid,
                                             const int* __restrict__ src,
                                             const float* __restrict__ norm,
                                             float* __restrict__ hpre,
                                             float* __restrict__ stats_h) {
  const int g = (blockIdx.x * blockDim.x + threadIdx.x) >> 3;  // node id (exact: 3125 blocks)
  const int lane = threadIdx.x & 7;
  float n0 = 0.f, n1 = 0.f, n2 = 0.f, n3 = 0.f;
  float d0 = 0.f, d1 = 0.f, d2 = 0.f, d3 = 0.f;

  const int lo = offs[g];
  const int hi = offs[g + 1];
  for (int p = lo; p < hi; ++p) {
    const int k = eid[p];
    const int sidx = src[k];
    float4 x = reinterpret_cast<const float4*>(eij)[(long long)k * 8 + lane];
    float4 hs = reinterpret_cast<const float4*>(hn)[(long long)sidx * 8 + lane];
    float g0 = 1.f / (1.f + __expf(-x.x));
    float g1 = 1.f / (1.f + __expf(-x.y));
    float g2 = 1.f / (1.f + __expf(-x.z));
    float g3 = 1.f / (1.f + __expf(-x.w));
    n0 += g0 * hs.x; n1 += g1 * hs.y; n2 += g2 * hs.z; n3 += g3 * hs.w;
    d0 += g0; d1 += g1; d2 += g2; d3 += g3;
  }

  float4 hv = reinterpret_cast<const float4*>(hn)[(long long)g * 8 + lane];
  float nm = norm[g];
  float y0 = (hv.x + n0 / (d0 + 1e-6f)) * nm;
  float y1 = (hv.y + n1 / (d1 + 1e-6f)) * nm;
  float y2 = (hv.z + n2 / (d2 + 1e-6f)) * nm;
  float y3 = (hv.w + n3 / (d3 + 1e-6f)) * nm;
  reinterpret_cast<float4*>(hpre)[(long long)g * 8 + lane] = make_float4(y0, y1, y2, y3);

  __shared__ float sh[64];
  if (threadIdx.x < 64) sh[threadIdx.x] = 0.f;
  __syncthreads();
  const int cb = lane * 4;
  atomicAdd(&sh[cb + 0], y0); atomicAdd(&sh[cb + 1], y1);
  atomicAdd(&sh[cb + 2], y2); atomicAdd(&sh[cb + 3], y3);
  atomicAdd(&sh[32 + cb + 0], y0 * y0); atomicAdd(&sh[32 + cb + 1], y1 * y1);
  atomicAdd(&sh[32 + cb + 2], y2 * y2); atomicAdd(&sh[32 + cb + 3], y3 * y3);
  __syncthreads();
  if (threadIdx.x < 64)
    atomicAdd(&stats_h[(blockIdx.x & (SCOPIES - 1)) * 64 + threadIdx.x], sh[threadIdx.x]);
}

// ---------------- kernel F: finalize BN statistics ----------------
__global__ void k_fin(const float* __restrict__ stats_e,
                      const float* __restrict__ stats_h,
                      float* __restrict__ fin) {
  int t = threadIdx.x;   // 64 threads
  if (t < 32) {
    float s = 0.f, q = 0.f;
    for (int c = 0; c < SCOPIES; ++c) {
      s += stats_h[c * 64 + t];
      q += stats_h[c * 64 + 32 + t];
    }
    float mean = s / (float)NN;
    float var = q / (float)NN - mean * mean;
    fin[t] = mean;
    fin[32 + t] = rsqrtf(var + 1e-5f);
  } else {
    int col = t - 32;
    float s = 0.f, q = 0.f;
    for (int c = 0; c < SCOPIES; ++c) {
      s += stats_e[c * 64 + col];
      q += stats_e[c * 64 + 32 + col];
    }
    float mean = s / (float)NE;
    float var = q / (float)NE - mean * mean;
    fin[64 + col] = mean;
    fin[96 + col] = rsqrtf(var + 1e-5f);
  }
}

// ---------------- kernel G: in-place BN + ReLU apply ----------------
__global__ __launch_bounds__(256) void k_apply(float* __restrict__ buf,
                                               long long nslots,
                                               const float* __restrict__ mean,
                                               const float* __restrict__ inv,
                                               const float* __restrict__ gamma,
                                               const float* __restrict__ beta) {
  long long i = (long long)blockIdx.x * blockDim.x + threadIdx.x;
  if (i >= nslots) return;
  const int cb = (int)(i & 7) * 4;
  float4 x = reinterpret_cast<float4*>(buf)[i];
  float y0 = fmaxf(0.f, (x.x - mean[cb + 0]) * inv[cb + 0] * gamma[cb + 0] + beta[cb + 0]);
  float y1 = fmaxf(0.f, (x.y - mean[cb + 1]) * inv[cb + 1] * gamma[cb + 1] + beta[cb + 1]);
  float y2 = fmaxf(0.f, (x.z - mean[cb + 2]) * inv[cb + 2] * gamma[cb + 2] + beta[cb + 2]);
  float y3 = fmaxf(0.f, (x.w - mean[cb + 3]) * inv[cb + 3] * gamma[cb + 3] + beta[cb + 3]);
  reinterpret_cast<float4*>(buf)[i] = make_float4(y0, y1, y2, y3);
}

extern "C" void kernel_launch(void* const* d_in, const int* in_sizes, int n_in,
                              void* d_out, int out_size, void* d_ws, size_t ws_size,
                              hipStream_t stream) {
  const float* h     = (const float*)d_in[0];
  const float* e     = (const float*)d_in[1];
  const float* norm  = (const float*)d_in[2];
  const int*   src   = (const int*)d_in[3];
  const int*   dst   = (const int*)d_in[4];
  const float* gh    = (const float*)d_in[5];
  const float* bh    = (const float*)d_in[6];
  const float* ge    = (const float*)d_in[7];
  const float* be    = (const float*)d_in[8];
  (void)in_sizes; (void)n_in; (void)out_size; (void)ws_size;

  float* ws   = (float*)d_ws;
  float* hn   = ws + OFF_HN;
  int*   deg  = (int*)(ws + OFF_DEG);
  float* se   = ws + OFF_SE;
  float* shh  = ws + OFF_SH;
  float* fin  = ws + OFF_FIN;
  int*   offs = (int*)(ws + OFF_OFFS);
  int*   curs = (int*)(ws + OFF_CURS);
  int*   eid  = (int*)(ws + OFF_EID);

  float* out  = (float*)d_out;
  float* hpre = out;                           // [NN*32] h output region
  float* eout = out + (long long)NN * DIMS;    // [NE*32] e output region (holds e_ij, then e_out)

  // zero deg + stats (contiguous: OFF_DEG .. OFF_FIN+128)
  hipMemsetAsync(deg, 0, (size_t)(OFF_FIN + 128 - OFF_DEG) * sizeof(float), stream);

  k_hn<<<(NN * 8 + 255) / 256, 256, 0, stream>>>(h, norm, hn);
  k_edge<<<4096, 256, 0, stream>>>(e, hn, src, dst, eout, deg, se);
  k_scan<<<1, 1024, 0, stream>>>(deg, offs, curs);
  k_scatter<<<(NE + 255) / 256, 256, 0, stream>>>(dst, curs, eid);
  k_agg<<<NN * 8 / 256, 256, 0, stream>>>(hn, eout, offs, eid, src, norm, hpre, shh);
  k_fin<<<1, 64, 0, stream>>>(se, shh, fin);
  k_apply<<<(NN * 8 + 255) / 256, 256, 0, stream>>>(hpre, (long long)NN * 8,
                                                    fin + 0, fin + 32, gh, bh);
  k_apply<<<((long long)NE * 8 + 255) / 256, 256, 0, stream>>>(eout, (long long)NE * 8,
                                                               fin + 64, fin + 96, ge, be);
}

// Round 3
// 454.363 us; speedup vs baseline: 3.0966x; 1.4672x over previous
//
#include <hip/hip_runtime.h>

#define NN 100000
#define NE 1600000
#define DIMS 32
static constexpr int SCOPIES = 32;

// hierarchical scan geometry
#define SCAN_NB  128
#define SCAN_NTH 256
#define SCAN_CPT 4    // 128*256*4 = 131072 >= 100000

// workspace layout (float offsets)
static constexpr long long OFF_HN   = 0;          // 3.2M floats
static constexpr long long OFF_DEG  = 3200000;    // 100000 ints   [zeroed]
static constexpr long long OFF_SE   = 3300000;    // 2048 floats   [zeroed]
static constexpr long long OFF_SH   = 3302048;    // 2048 floats   [zeroed]
static constexpr long long OFF_FIN  = 3304096;    // 128 floats
static constexpr long long OFF_OFFS = 3304224;    // 100001 ints
static constexpr long long OFF_CURS = 3404232;    // 100000 ints
static constexpr long long OFF_EID  = 3504232;    // 1.6M ints
static constexpr long long OFF_TEX  = 5104232;    // 32768 ints (per-thread excl prefixes)
static constexpr long long OFF_PART = 5137000;    // 128 ints (block partials)

// ---------------- kernel A: hn = h * norm ----------------
__global__ __launch_bounds__(256) void k_hn(const float* __restrict__ h,
                                            const float* __restrict__ norm,
                                            float* __restrict__ hn) {
  int i = blockIdx.x * blockDim.x + threadIdx.x;   // float4 slots, NN*8
  if (i >= NN * 8) return;
  float4 v = reinterpret_cast<const float4*>(h)[i];
  float nm = norm[i >> 3];
  v.x *= nm; v.y *= nm; v.z *= nm; v.w *= nm;
  reinterpret_cast<float4*>(hn)[i] = v;
}

// ---------------- kernel B: e_ij compute + dst histogram + e-stats ----------------
__global__ __launch_bounds__(256) void k_edge(const float* __restrict__ e,
                                              const float* __restrict__ hn,
                                              const int* __restrict__ src,
                                              const int* __restrict__ dst,
                                              float* __restrict__ eij,
                                              int* __restrict__ deg,
                                              float* __restrict__ stats_e) {
  const int lane = threadIdx.x & 7;                 // 8 threads per edge
  const int slot0 = (blockIdx.x * blockDim.x + threadIdx.x) >> 3;
  const int nslots = (gridDim.x * blockDim.x) >> 3;
  float s0 = 0.f, s1 = 0.f, s2 = 0.f, s3 = 0.f;
  float q0 = 0.f, q1 = 0.f, q2 = 0.f, q3 = 0.f;

  for (int k = slot0; k < NE; k += nslots) {
    const int sidx = src[k];
    const int didx = dst[k];
    float4 ev = reinterpret_cast<const float4*>(e)[(long long)k * 8 + lane];
    float4 hs = reinterpret_cast<const float4*>(hn)[(long long)sidx * 8 + lane];
    float4 hd = reinterpret_cast<const float4*>(hn)[(long long)didx * 8 + lane];
    float x0 = ev.x + hs.x + hd.x;
    float x1 = ev.y + hs.y + hd.y;
    float x2 = ev.z + hs.z + hd.z;
    float x3 = ev.w + hs.w + hd.w;
    reinterpret_cast<float4*>(eij)[(long long)k * 8 + lane] = make_float4(x0, x1, x2, x3);
    if (lane == 0) atomicAdd(&deg[didx], 1);
    s0 += x0; s1 += x1; s2 += x2; s3 += x3;
    q0 += x0 * x0; q1 += x1 * x1; q2 += x2 * x2; q3 += x3 * x3;
  }

  __shared__ float sh[64];
  if (threadIdx.x < 64) sh[threadIdx.x] = 0.f;
  __syncthreads();
  const int cb = lane * 4;
  atomicAdd(&sh[cb + 0], s0); atomicAdd(&sh[cb + 1], s1);
  atomicAdd(&sh[cb + 2], s2); atomicAdd(&sh[cb + 3], s3);
  atomicAdd(&sh[32 + cb + 0], q0); atomicAdd(&sh[32 + cb + 1], q1);
  atomicAdd(&sh[32 + cb + 2], q2); atomicAdd(&sh[32 + cb + 3], q3);
  __syncthreads();
  if (threadIdx.x < 64)
    atomicAdd(&stats_e[(blockIdx.x & (SCOPIES - 1)) * 64 + threadIdx.x], sh[threadIdx.x]);
}

// ---------------- scan phase A: per-thread chunk sums + in-block scan ----------------
__global__ __launch_bounds__(SCAN_NTH) void k_scanA(const int* __restrict__ deg,
                                                    int* __restrict__ texcl,
                                                    int* __restrict__ partials) {
  const int t = threadIdx.x, b = blockIdx.x;
  const int tid = b * SCAN_NTH + t;
  const int lo = tid * SCAN_CPT;
  const int hi = (lo + SCAN_CPT < NN) ? lo + SCAN_CPT : NN;
  int s = 0;
  for (int i = lo; i < hi; ++i) s += deg[i];
  __shared__ int sh[SCAN_NTH];
  sh[t] = s;
  __syncthreads();
  for (int d = 1; d < SCAN_NTH; d <<= 1) {
    int v = (t >= d) ? sh[t - d] : 0;
    __syncthreads();
    sh[t] += v;
    __syncthreads();
  }
  texcl[b * SCAN_NTH + t] = sh[t] - s;     // exclusive within block
  if (t == SCAN_NTH - 1) partials[b] = sh[t];
}

// ---------------- scan phase B: scan the 128 block partials (in place -> exclusive) --
__global__ __launch_bounds__(SCAN_NB) void k_scanB(int* __restrict__ partials) {
  __shared__ int sh[SCAN_NB];
  const int t = threadIdx.x;
  int v = partials[t];
  sh[t] = v;
  __syncthreads();
  for (int d = 1; d < SCAN_NB; d <<= 1) {
    int u = (t >= d) ? sh[t - d] : 0;
    __syncthreads();
    sh[t] += u;
    __syncthreads();
  }
  partials[t] = sh[t] - v;                 // exclusive
}

// ---------------- scan phase C: write offs/curs ----------------
__global__ __launch_bounds__(SCAN_NTH) void k_scanC(const int* __restrict__ deg,
                                                    const int* __restrict__ texcl,
                                                    const int* __restrict__ partials,
                                                    int* __restrict__ offs,
                                                    int* __restrict__ curs) {
  const int t = threadIdx.x, b = blockIdx.x;
  const int tid = b * SCAN_NTH + t;
  const int lo = tid * SCAN_CPT;
  const int hi = (lo + SCAN_CPT < NN) ? lo + SCAN_CPT : NN;
  int run = partials[b] + texcl[b * SCAN_NTH + t];
  for (int i = lo; i < hi; ++i) {
    offs[i] = run;
    curs[i] = run;
    run += deg[i];
  }
  if (tid == 0) offs[NN] = NE;
}

// ---------------- kernel D: scatter edge ids into CSR ----------------
__global__ __launch_bounds__(256) void k_scatter(const int* __restrict__ dst,
                                                 int* __restrict__ curs,
                                                 int* __restrict__ eid) {
  int k = blockIdx.x * blockDim.x + threadIdx.x;
  if (k >= NE) return;
  int pos = atomicAdd(&curs[dst[k]], 1);
  eid[pos] = k;
}

// ---------------- kernel E: gather-aggregate + node update + h-stats ----------------
__global__ __launch_bounds__(256) void k_agg(const float* __restrict__ hn,
                                             const float* __restrict__ eij,
                                             const int* __restrict__ offs,
                                             const int* __restrict__ eid,
                                             const int* __restrict__ src,
                                             const float* __restrict__ norm,
                                             float* __restrict__ hpre,
                                             float* __restrict__ stats_h) {
  const int g = (blockIdx.x * blockDim.x + threadIdx.x) >> 3;  // node id (exact: 3125 blocks)
  const int lane = threadIdx.x & 7;
  float n0 = 0.f, n1 = 0.f, n2 = 0.f, n3 = 0.f;
  float d0 = 0.f, d1 = 0.f, d2 = 0.f, d3 = 0.f;

  const int lo = offs[g];
  const int hi = offs[g + 1];
  for (int p = lo; p < hi; ++p) {
    const int k = eid[p];
    const int sidx = src[k];
    float4 x = reinterpret_cast<const float4*>(eij)[(long long)k * 8 + lane];
    float4 hs = reinterpret_cast<const float4*>(hn)[(long long)sidx * 8 + lane];
    float g0 = 1.f / (1.f + __expf(-x.x));
    float g1 = 1.f / (1.f + __expf(-x.y));
    float g2 = 1.f / (1.f + __expf(-x.z));
    float g3 = 1.f / (1.f + __expf(-x.w));
    n0 += g0 * hs.x; n1 += g1 * hs.y; n2 += g2 * hs.z; n3 += g3 * hs.w;
    d0 += g0; d1 += g1; d2 += g2; d3 += g3;
  }

  float4 hv = reinterpret_cast<const float4*>(hn)[(long long)g * 8 + lane];
  float nm = norm[g];
  float y0 = (hv.x + n0 / (d0 + 1e-6f)) * nm;
  float y1 = (hv.y + n1 / (d1 + 1e-6f)) * nm;
  float y2 = (hv.z + n2 / (d2 + 1e-6f)) * nm;
  float y3 = (hv.w + n3 / (d3 + 1e-6f)) * nm;
  reinterpret_cast<float4*>(hpre)[(long long)g * 8 + lane] = make_float4(y0, y1, y2, y3);

  __shared__ float sh[64];
  if (threadIdx.x < 64) sh[threadIdx.x] = 0.f;
  __syncthreads();
  const int cb = lane * 4;
  atomicAdd(&sh[cb + 0], y0); atomicAdd(&sh[cb + 1], y1);
  atomicAdd(&sh[cb + 2], y2); atomicAdd(&sh[cb + 3], y3);
  atomicAdd(&sh[32 + cb + 0], y0 * y0); atomicAdd(&sh[32 + cb + 1], y1 * y1);
  atomicAdd(&sh[32 + cb + 2], y2 * y2); atomicAdd(&sh[32 + cb + 3], y3 * y3);
  __syncthreads();
  if (threadIdx.x < 64)
    atomicAdd(&stats_h[(blockIdx.x & (SCOPIES - 1)) * 64 + threadIdx.x], sh[threadIdx.x]);
}

// ---------------- kernel F: finalize BN statistics ----------------
__global__ void k_fin(const float* __restrict__ stats_e,
                      const float* __restrict__ stats_h,
                      float* __restrict__ fin) {
  int t = threadIdx.x;   // 64 threads
  if (t < 32) {
    float s = 0.f, q = 0.f;
    for (int c = 0; c < SCOPIES; ++c) {
      s += stats_h[c * 64 + t];
      q += stats_h[c * 64 + 32 + t];
    }
    float mean = s / (float)NN;
    float var = q / (float)NN - mean * mean;
    fin[t] = mean;
    fin[32 + t] = rsqrtf(var + 1e-5f);
  } else {
    int col = t - 32;
    float s = 0.f, q = 0.f;
    for (int c = 0; c < SCOPIES; ++c) {
      s += stats_e[c * 64 + col];
      q += stats_e[c * 64 + 32 + col];
    }
    float mean = s / (float)NE;
    float var = q / (float)NE - mean * mean;
    fin[64 + col] = mean;
    fin[96 + col] = rsqrtf(var + 1e-5f);
  }
}

// ---------------- kernel G: in-place BN + ReLU apply ----------------
__global__ __launch_bounds__(256) void k_apply(float* __restrict__ buf,
                                               long long nslots,
                                               const float* __restrict__ mean,
                                               const float* __restrict__ inv,
                                               const float* __restrict__ gamma,
                                               const float* __restrict__ beta) {
  long long i = (long long)blockIdx.x * blockDim.x + threadIdx.x;
  if (i >= nslots) return;
  const int cb = (int)(i & 7) * 4;
  float4 x = reinterpret_cast<float4*>(buf)[i];
  float y0 = fmaxf(0.f, (x.x - mean[cb + 0]) * inv[cb + 0] * gamma[cb + 0] + beta[cb + 0]);
  float y1 = fmaxf(0.f, (x.y - mean[cb + 1]) * inv[cb + 1] * gamma[cb + 1] + beta[cb + 1]);
  float y2 = fmaxf(0.f, (x.z - mean[cb + 2]) * inv[cb + 2] * gamma[cb + 2] + beta[cb + 2]);
  float y3 = fmaxf(0.f, (x.w - mean[cb + 3]) * inv[cb + 3] * gamma[cb + 3] + beta[cb + 3]);
  reinterpret_cast<float4*>(buf)[i] = make_float4(y0, y1, y2, y3);
}

extern "C" void kernel_launch(void* const* d_in, const int* in_sizes, int n_in,
                              void* d_out, int out_size, void* d_ws, size_t ws_size,
                              hipStream_t stream) {
  const float* h     = (const float*)d_in[0];
  const float* e     = (const float*)d_in[1];
  const float* norm  = (const float*)d_in[2];
  const int*   src   = (const int*)d_in[3];
  const int*   dst   = (const int*)d_in[4];
  const float* gh    = (const float*)d_in[5];
  const float* bh    = (const float*)d_in[6];
  const float* ge    = (const float*)d_in[7];
  const float* be    = (const float*)d_in[8];
  (void)in_sizes; (void)n_in; (void)out_size; (void)ws_size;

  float* ws    = (float*)d_ws;
  float* hn    = ws + OFF_HN;
  int*   deg   = (int*)(ws + OFF_DEG);
  float* se    = ws + OFF_SE;
  float* shh   = ws + OFF_SH;
  float* fin   = ws + OFF_FIN;
  int*   offs  = (int*)(ws + OFF_OFFS);
  int*   curs  = (int*)(ws + OFF_CURS);
  int*   eid   = (int*)(ws + OFF_EID);
  int*   texcl = (int*)(ws + OFF_TEX);
  int*   parts = (int*)(ws + OFF_PART);

  float* out  = (float*)d_out;
  float* hpre = out;                           // [NN*32] h output region
  float* eout = out + (long long)NN * DIMS;    // [NE*32] e output region (holds e_ij, then e_out)

  // zero deg + stats (contiguous: OFF_DEG .. OFF_FIN+128)
  hipMemsetAsync(deg, 0, (size_t)(OFF_FIN + 128 - OFF_DEG) * sizeof(float), stream);

  k_hn<<<(NN * 8 + 255) / 256, 256, 0, stream>>>(h, norm, hn);
  k_edge<<<4096, 256, 0, stream>>>(e, hn, src, dst, eout, deg, se);
  k_scanA<<<SCAN_NB, SCAN_NTH, 0, stream>>>(deg, texcl, parts);
  k_scanB<<<1, SCAN_NB, 0, stream>>>(parts);
  k_scanC<<<SCAN_NB, SCAN_NTH, 0, stream>>>(deg, texcl, parts, offs, curs);
  k_scatter<<<(NE + 255) / 256, 256, 0, stream>>>(dst, curs, eid);
  k_agg<<<NN * 8 / 256, 256, 0, stream>>>(hn, eout, offs, eid, src, norm, hpre, shh);
  k_fin<<<1, 64, 0, stream>>>(se, shh, fin);
  k_apply<<<(NN * 8 + 255) / 256, 256, 0, stream>>>(hpre, (long long)NN * 8,
                                                    fin + 0, fin + 32, gh, bh);
  k_apply<<<((long long)NE * 8 + 255) / 256, 256, 0, stream>>>(eout, (long long)NE * 8,
                                                               fin + 64, fin + 96, ge, be);
}

// Round 4
// 349.206 us; speedup vs baseline: 4.0291x; 1.3011x over previous
//
#include <hip/hip_runtime.h>

#define NN 100000
#define NE 1600000
#define DIMS 32
static constexpr int SCOPIES = 32;

// hierarchical scan geometry
#define SCAN_NB  128
#define SCAN_NTH 256
#define SCAN_CPT 4    // 128*256*4 = 131072 >= 100000

// workspace layout (float offsets)
static constexpr long long OFF_HN   = 0;          // 3.2M floats
static constexpr long long OFF_DEG  = 3200000;    // 100000 ints   [zeroed]
static constexpr long long OFF_SE   = 3300000;    // 2048 floats   [zeroed]
static constexpr long long OFF_SH   = 3302048;    // 2048 floats   [zeroed]
static constexpr long long OFF_FIN  = 3304096;    // 128 floats: [mh|ih|me|ie]
static constexpr long long OFF_OFFS = 3304224;    // 100001 ints
static constexpr long long OFF_CURS = 3404232;    // 100000 ints
static constexpr long long OFF_TEX  = 3504232;    // 32768 ints
static constexpr long long OFF_PART = 3537000;    // 128 ints
static constexpr long long OFF_EID2 = 3537128;    // 3.2M ints (1.6M int2), 8B-aligned

// ---------------- kernel A: hn = h * norm ----------------
__global__ __launch_bounds__(256) void k_hn(const float* __restrict__ h,
                                            const float* __restrict__ norm,
                                            float* __restrict__ hn) {
  int i = blockIdx.x * blockDim.x + threadIdx.x;   // float4 slots, NN*8
  if (i >= NN * 8) return;
  float4 v = reinterpret_cast<const float4*>(h)[i];
  float nm = norm[i >> 3];
  v.x *= nm; v.y *= nm; v.z *= nm; v.w *= nm;
  reinterpret_cast<float4*>(hn)[i] = v;
}

// ---------------- kernel H: dst-degree histogram ----------------
__global__ __launch_bounds__(256) void k_hist(const int* __restrict__ dst,
                                              int* __restrict__ deg) {
  int i = blockIdx.x * blockDim.x + threadIdx.x;
  if (i >= NE / 4) return;
  int4 d = reinterpret_cast<const int4*>(dst)[i];
  atomicAdd(&deg[d.x], 1);
  atomicAdd(&deg[d.y], 1);
  atomicAdd(&deg[d.z], 1);
  atomicAdd(&deg[d.w], 1);
}

// ---------------- scan phase A ----------------
__global__ __launch_bounds__(SCAN_NTH) void k_scanA(const int* __restrict__ deg,
                                                    int* __restrict__ texcl,
                                                    int* __restrict__ partials) {
  const int t = threadIdx.x, b = blockIdx.x;
  const int tid = b * SCAN_NTH + t;
  const int lo = tid * SCAN_CPT;
  const int hi = (lo + SCAN_CPT < NN) ? lo + SCAN_CPT : NN;
  int s = 0;
  for (int i = lo; i < hi; ++i) s += deg[i];
  __shared__ int sh[SCAN_NTH];
  sh[t] = s;
  __syncthreads();
  for (int d = 1; d < SCAN_NTH; d <<= 1) {
    int v = (t >= d) ? sh[t - d] : 0;
    __syncthreads();
    sh[t] += v;
    __syncthreads();
  }
  texcl[b * SCAN_NTH + t] = sh[t] - s;
  if (t == SCAN_NTH - 1) partials[b] = sh[t];
}

// ---------------- scan phase B ----------------
__global__ __launch_bounds__(SCAN_NB) void k_scanB(int* __restrict__ partials) {
  __shared__ int sh[SCAN_NB];
  const int t = threadIdx.x;
  int v = partials[t];
  sh[t] = v;
  __syncthreads();
  for (int d = 1; d < SCAN_NB; d <<= 1) {
    int u = (t >= d) ? sh[t - d] : 0;
    __syncthreads();
    sh[t] += u;
    __syncthreads();
  }
  partials[t] = sh[t] - v;
}

// ---------------- scan phase C ----------------
__global__ __launch_bounds__(SCAN_NTH) void k_scanC(const int* __restrict__ deg,
                                                    const int* __restrict__ texcl,
                                                    const int* __restrict__ partials,
                                                    int* __restrict__ offs,
                                                    int* __restrict__ curs) {
  const int t = threadIdx.x, b = blockIdx.x;
  const int tid = b * SCAN_NTH + t;
  const int lo = tid * SCAN_CPT;
  const int hi = (lo + SCAN_CPT < NN) ? lo + SCAN_CPT : NN;
  int run = partials[b] + texcl[b * SCAN_NTH + t];
  for (int i = lo; i < hi; ++i) {
    offs[i] = run;
    curs[i] = run;
    run += deg[i];
  }
  if (tid == 0) offs[NN] = NE;
}

// ---- kernel B: e-stats + fused CSR scatter (no e_ij store) ----
__global__ __launch_bounds__(256) void k_edge(const float* __restrict__ e,
                                              const float* __restrict__ hn,
                                              const int* __restrict__ src,
                                              const int* __restrict__ dst,
                                              int* __restrict__ curs,
                                              int2* __restrict__ eid2,
                                              float* __restrict__ stats_e) {
  const int lane = threadIdx.x & 7;                 // 8 threads per edge
  const int slot0 = (blockIdx.x * blockDim.x + threadIdx.x) >> 3;
  const int nslots = (gridDim.x * blockDim.x) >> 3;
  float s0 = 0.f, s1 = 0.f, s2 = 0.f, s3 = 0.f;
  float q0 = 0.f, q1 = 0.f, q2 = 0.f, q3 = 0.f;

  for (int k = slot0; k < NE; k += nslots) {
    const int sidx = src[k];
    const int didx = dst[k];
    float4 ev = reinterpret_cast<const float4*>(e)[(long long)k * 8 + lane];
    float4 hs = reinterpret_cast<const float4*>(hn)[(long long)sidx * 8 + lane];
    float4 hd = reinterpret_cast<const float4*>(hn)[(long long)didx * 8 + lane];
    float x0 = ev.x + hs.x + hd.x;
    float x1 = ev.y + hs.y + hd.y;
    float x2 = ev.z + hs.z + hd.z;
    float x3 = ev.w + hs.w + hd.w;
    if (lane == 0) {
      int pos = atomicAdd(&curs[didx], 1);
      eid2[pos] = make_int2(k, sidx);
    }
    s0 += x0; s1 += x1; s2 += x2; s3 += x3;
    q0 += x0 * x0; q1 += x1 * x1; q2 += x2 * x2; q3 += x3 * x3;
  }

  __shared__ float sh[64];
  if (threadIdx.x < 64) sh[threadIdx.x] = 0.f;
  __syncthreads();
  const int cb = lane * 4;
  atomicAdd(&sh[cb + 0], s0); atomicAdd(&sh[cb + 1], s1);
  atomicAdd(&sh[cb + 2], s2); atomicAdd(&sh[cb + 3], s3);
  atomicAdd(&sh[32 + cb + 0], q0); atomicAdd(&sh[32 + cb + 1], q1);
  atomicAdd(&sh[32 + cb + 2], q2); atomicAdd(&sh[32 + cb + 3], q3);
  __syncthreads();
  if (threadIdx.x < 64)
    atomicAdd(&stats_e[(blockIdx.x & (SCOPIES - 1)) * 64 + threadIdx.x], sh[threadIdx.x]);
}

// ---------------- finalize e-stats (runs before k_agg) ----------------
__global__ void k_fin_e(const float* __restrict__ stats_e, float* __restrict__ fin) {
  int t = threadIdx.x;   // 32 threads
  float s = 0.f, q = 0.f;
  for (int c = 0; c < SCOPIES; ++c) {
    s += stats_e[c * 64 + t];
    q += stats_e[c * 64 + 32 + t];
  }
  float mean = s / (float)NE;
  float var = q / (float)NE - mean * mean;
  fin[64 + t] = mean;
  fin[96 + t] = rsqrtf(var + 1e-5f);
}

// ---- kernel E: gather-aggregate + node update + h-stats + e_out write ----
__global__ __launch_bounds__(256) void k_agg(const float* __restrict__ e,
                                             const float* __restrict__ hn,
                                             const int* __restrict__ offs,
                                             const int2* __restrict__ eid2,
                                             const float* __restrict__ norm,
                                             const float* __restrict__ fin,
                                             const float* __restrict__ ge,
                                             const float* __restrict__ be,
                                             float* __restrict__ hpre,
                                             float* __restrict__ eout,
                                             float* __restrict__ stats_h) {
  const int g = (blockIdx.x * blockDim.x + threadIdx.x) >> 3;  // node id (3125 blocks exact)
  const int lane = threadIdx.x & 7;
  const int cb = lane * 4;
  float n0 = 0.f, n1 = 0.f, n2 = 0.f, n3 = 0.f;
  float d0 = 0.f, d1 = 0.f, d2 = 0.f, d3 = 0.f;

  // BN-e params for this lane's 4 columns
  float me0 = fin[64 + cb + 0], me1 = fin[64 + cb + 1], me2 = fin[64 + cb + 2], me3 = fin[64 + cb + 3];
  float ie0 = fin[96 + cb + 0], ie1 = fin[96 + cb + 1], ie2 = fin[96 + cb + 2], ie3 = fin[96 + cb + 3];
  float ge0 = ge[cb + 0], ge1 = ge[cb + 1], ge2 = ge[cb + 2], ge3 = ge[cb + 3];
  float be0 = be[cb + 0], be1 = be[cb + 1], be2 = be[cb + 2], be3 = be[cb + 3];

  float4 hv = reinterpret_cast<const float4*>(hn)[(long long)g * 8 + lane];

  const int lo = offs[g];
  const int hi = offs[g + 1];
  int2 nk;
  if (lo < hi) nk = eid2[lo];
  for (int p = lo; p < hi; ++p) {
    int2 kk = nk;
    if (p + 1 < hi) nk = eid2[p + 1];
    float4 ev = reinterpret_cast<const float4*>(e)[(long long)kk.x * 8 + lane];
    float4 hs = reinterpret_cast<const float4*>(hn)[(long long)kk.y * 8 + lane];
    float x0 = ev.x + hs.x + hv.x;
    float x1 = ev.y + hs.y + hv.y;
    float x2 = ev.z + hs.z + hv.z;
    float x3 = ev.w + hs.w + hv.w;
    float g0 = 1.f / (1.f + __expf(-x0));
    float g1 = 1.f / (1.f + __expf(-x1));
    float g2 = 1.f / (1.f + __expf(-x2));
    float g3 = 1.f / (1.f + __expf(-x3));
    n0 += g0 * hs.x; n1 += g1 * hs.y; n2 += g2 * hs.z; n3 += g3 * hs.w;
    d0 += g0; d1 += g1; d2 += g2; d3 += g3;
    // e_out = relu(bn(e_ij)) written directly (CSR covers every edge once)
    float o0 = fmaxf(0.f, (x0 - me0) * ie0 * ge0 + be0);
    float o1 = fmaxf(0.f, (x1 - me1) * ie1 * ge1 + be1);
    float o2 = fmaxf(0.f, (x2 - me2) * ie2 * ge2 + be2);
    float o3 = fmaxf(0.f, (x3 - me3) * ie3 * ge3 + be3);
    reinterpret_cast<float4*>(eout)[(long long)kk.x * 8 + lane] = make_float4(o0, o1, o2, o3);
  }

  float nm = norm[g];
  float y0 = (hv.x + n0 / (d0 + 1e-6f)) * nm;
  float y1 = (hv.y + n1 / (d1 + 1e-6f)) * nm;
  float y2 = (hv.z + n2 / (d2 + 1e-6f)) * nm;
  float y3 = (hv.w + n3 / (d3 + 1e-6f)) * nm;
  reinterpret_cast<float4*>(hpre)[(long long)g * 8 + lane] = make_float4(y0, y1, y2, y3);

  __shared__ float sh[64];
  if (threadIdx.x < 64) sh[threadIdx.x] = 0.f;
  __syncthreads();
  atomicAdd(&sh[cb + 0], y0); atomicAdd(&sh[cb + 1], y1);
  atomicAdd(&sh[cb + 2], y2); atomicAdd(&sh[cb + 3], y3);
  atomicAdd(&sh[32 + cb + 0], y0 * y0); atomicAdd(&sh[32 + cb + 1], y1 * y1);
  atomicAdd(&sh[32 + cb + 2], y2 * y2); atomicAdd(&sh[32 + cb + 3], y3 * y3);
  __syncthreads();
  if (threadIdx.x < 64)
    atomicAdd(&stats_h[(blockIdx.x & (SCOPIES - 1)) * 64 + threadIdx.x], sh[threadIdx.x]);
}

// ---------------- finalize h-stats ----------------
__global__ void k_fin_h(const float* __restrict__ stats_h, float* __restrict__ fin) {
  int t = threadIdx.x;   // 32 threads
  float s = 0.f, q = 0.f;
  for (int c = 0; c < SCOPIES; ++c) {
    s += stats_h[c * 64 + t];
    q += stats_h[c * 64 + 32 + t];
  }
  float mean = s / (float)NN;
  float var = q / (float)NN - mean * mean;
  fin[t] = mean;
  fin[32 + t] = rsqrtf(var + 1e-5f);
}

// ---------------- in-place BN + ReLU apply (h only) ----------------
__global__ __launch_bounds__(256) void k_apply(float* __restrict__ buf,
                                               long long nslots,
                                               const float* __restrict__ mean,
                                               const float* __restrict__ inv,
                                               const float* __restrict__ gamma,
                                               const float* __restrict__ beta) {
  long long i = (long long)blockIdx.x * blockDim.x + threadIdx.x;
  if (i >= nslots) return;
  const int cb = (int)(i & 7) * 4;
  float4 x = reinterpret_cast<float4*>(buf)[i];
  float y0 = fmaxf(0.f, (x.x - mean[cb + 0]) * inv[cb + 0] * gamma[cb + 0] + beta[cb + 0]);
  float y1 = fmaxf(0.f, (x.y - mean[cb + 1]) * inv[cb + 1] * gamma[cb + 1] + beta[cb + 1]);
  float y2 = fmaxf(0.f, (x.z - mean[cb + 2]) * inv[cb + 2] * gamma[cb + 2] + beta[cb + 2]);
  float y3 = fmaxf(0.f, (x.w - mean[cb + 3]) * inv[cb + 3] * gamma[cb + 3] + beta[cb + 3]);
  reinterpret_cast<float4*>(buf)[i] = make_float4(y0, y1, y2, y3);
}

extern "C" void kernel_launch(void* const* d_in, const int* in_sizes, int n_in,
                              void* d_out, int out_size, void* d_ws, size_t ws_size,
                              hipStream_t stream) {
  const float* h     = (const float*)d_in[0];
  const float* e     = (const float*)d_in[1];
  const float* norm  = (const float*)d_in[2];
  const int*   src   = (const int*)d_in[3];
  const int*   dst   = (const int*)d_in[4];
  const float* gh    = (const float*)d_in[5];
  const float* bh    = (const float*)d_in[6];
  const float* ge    = (const float*)d_in[7];
  const float* be    = (const float*)d_in[8];
  (void)in_sizes; (void)n_in; (void)out_size; (void)ws_size;

  float* ws    = (float*)d_ws;
  float* hn    = ws + OFF_HN;
  int*   deg   = (int*)(ws + OFF_DEG);
  float* se    = ws + OFF_SE;
  float* shh   = ws + OFF_SH;
  float* fin   = ws + OFF_FIN;
  int*   offs  = (int*)(ws + OFF_OFFS);
  int*   curs  = (int*)(ws + OFF_CURS);
  int*   texcl = (int*)(ws + OFF_TEX);
  int*   parts = (int*)(ws + OFF_PART);
  int2*  eid2  = (int2*)(ws + OFF_EID2);

  float* out  = (float*)d_out;
  float* hpre = out;                           // [NN*32] h output region
  float* eout = out + (long long)NN * DIMS;    // [NE*32] e output region

  // zero deg + stats (contiguous: OFF_DEG .. OFF_SH+2048)
  hipMemsetAsync(deg, 0, (size_t)(OFF_FIN - OFF_DEG) * sizeof(float), stream);

  k_hn<<<(NN * 8 + 255) / 256, 256, 0, stream>>>(h, norm, hn);
  k_hist<<<(NE / 4 + 255) / 256, 256, 0, stream>>>(dst, deg);
  k_scanA<<<SCAN_NB, SCAN_NTH, 0, stream>>>(deg, texcl, parts);
  k_scanB<<<1, SCAN_NB, 0, stream>>>(parts);
  k_scanC<<<SCAN_NB, SCAN_NTH, 0, stream>>>(deg, texcl, parts, offs, curs);
  k_edge<<<4096, 256, 0, stream>>>(e, hn, src, dst, curs, eid2, se);
  k_fin_e<<<1, 32, 0, stream>>>(se, fin);
  k_agg<<<NN * 8 / 256, 256, 0, stream>>>(e, hn, offs, eid2, norm, fin, ge, be,
                                          hpre, eout, shh);
  k_fin_h<<<1, 32, 0, stream>>>(shh, fin);
  k_apply<<<(NN * 8 + 255) / 256, 256, 0, stream>>>(hpre, (long long)NN * 8,
                                                    fin + 0, fin + 32, gh, bh);
}

// Round 6
// 335.452 us; speedup vs baseline: 4.1943x; 1.0410x over previous
//
#include <hip/hip_runtime.h>

#define NN 100000
#define NE 1600000
#define DIMS 32
static constexpr int SCOPIES = 32;

typedef float fx4 __attribute__((ext_vector_type(4)));   // native vec for nontemporal

// hierarchical scan geometry
#define SCAN_NB  128
#define SCAN_NTH 256
#define SCAN_CPT 4    // 128*256*4 = 131072 >= 100000

// workspace layout (float offsets)
static constexpr long long OFF_HN   = 0;          // 3.2M floats
static constexpr long long OFF_DEG  = 3200000;    // 100000 ints   [zeroed]
static constexpr long long OFF_SE   = 3300000;    // 2048 floats   [zeroed]
static constexpr long long OFF_SH   = 3302048;    // 2048 floats   [zeroed]
static constexpr long long OFF_FIN  = 3304096;    // 128 floats: [mh|ih|me|ie]
static constexpr long long OFF_OFFS = 3304224;    // 100001 ints
static constexpr long long OFF_CURS = 3404232;    // 100000 ints
static constexpr long long OFF_TEX  = 3504232;    // 32768 ints
static constexpr long long OFF_PART = 3537000;    // 128 ints
static constexpr long long OFF_EID2 = 3537128;    // 3.2M+ ints (1.6M int2 + pad)

// ---------------- kernel A: hn = h * norm ----------------
__global__ __launch_bounds__(256) void k_hn(const float* __restrict__ h,
                                            const float* __restrict__ norm,
                                            float* __restrict__ hn) {
  int i = blockIdx.x * blockDim.x + threadIdx.x;   // float4 slots, NN*8
  if (i >= NN * 8) return;
  float4 v = reinterpret_cast<const float4*>(h)[i];
  float nm = norm[i >> 3];
  v.x *= nm; v.y *= nm; v.z *= nm; v.w *= nm;
  reinterpret_cast<float4*>(hn)[i] = v;
}

// ---------------- kernel H: dst-degree histogram ----------------
__global__ __launch_bounds__(256) void k_hist(const int* __restrict__ dst,
                                              int* __restrict__ deg) {
  int i = blockIdx.x * blockDim.x + threadIdx.x;
  if (i >= NE / 4) return;
  int4 d = reinterpret_cast<const int4*>(dst)[i];
  atomicAdd(&deg[d.x], 1);
  atomicAdd(&deg[d.y], 1);
  atomicAdd(&deg[d.z], 1);
  atomicAdd(&deg[d.w], 1);
}

// ---------------- scan phase A ----------------
__global__ __launch_bounds__(SCAN_NTH) void k_scanA(const int* __restrict__ deg,
                                                    int* __restrict__ texcl,
                                                    int* __restrict__ partials) {
  const int t = threadIdx.x, b = blockIdx.x;
  const int tid = b * SCAN_NTH + t;
  const int lo = tid * SCAN_CPT;
  const int hi = (lo + SCAN_CPT < NN) ? lo + SCAN_CPT : NN;
  int s = 0;
  for (int i = lo; i < hi; ++i) s += deg[i];
  __shared__ int sh[SCAN_NTH];
  sh[t] = s;
  __syncthreads();
  for (int d = 1; d < SCAN_NTH; d <<= 1) {
    int v = (t >= d) ? sh[t - d] : 0;
    __syncthreads();
    sh[t] += v;
    __syncthreads();
  }
  texcl[b * SCAN_NTH + t] = sh[t] - s;
  if (t == SCAN_NTH - 1) partials[b] = sh[t];
}

// ---------------- scan phase B ----------------
__global__ __launch_bounds__(SCAN_NB) void k_scanB(int* __restrict__ partials) {
  __shared__ int sh[SCAN_NB];
  const int t = threadIdx.x;
  int v = partials[t];
  sh[t] = v;
  __syncthreads();
  for (int d = 1; d < SCAN_NB; d <<= 1) {
    int u = (t >= d) ? sh[t - d] : 0;
    __syncthreads();
    sh[t] += u;
    __syncthreads();
  }
  partials[t] = sh[t] - v;
}

// ---------------- scan phase C ----------------
__global__ __launch_bounds__(SCAN_NTH) void k_scanC(const int* __restrict__ deg,
                                                    const int* __restrict__ texcl,
                                                    const int* __restrict__ partials,
                                                    int* __restrict__ offs,
                                                    int* __restrict__ curs) {
  const int t = threadIdx.x, b = blockIdx.x;
  const int tid = b * SCAN_NTH + t;
  const int lo = tid * SCAN_CPT;
  const int hi = (lo + SCAN_CPT < NN) ? lo + SCAN_CPT : NN;
  int run = partials[b] + texcl[b * SCAN_NTH + t];
  for (int i = lo; i < hi; ++i) {
    offs[i] = run;
    curs[i] = run;
    run += deg[i];
  }
  if (tid == 0) offs[NN] = NE;
}

// ---- kernel B: e-stats + fused CSR scatter, 2-stage software pipeline ----
__global__ __launch_bounds__(256) void k_edge(const float* __restrict__ e,
                                              const float* __restrict__ hn,
                                              const int* __restrict__ src,
                                              const int* __restrict__ dst,
                                              int* __restrict__ curs,
                                              int2* __restrict__ eid2,
                                              float* __restrict__ stats_e) {
  const int lane = threadIdx.x & 7;                 // 8 threads per edge
  const int slot0 = (blockIdx.x * blockDim.x + threadIdx.x) >> 3;
  const int nslots = (gridDim.x * blockDim.x) >> 3;
  float s0 = 0.f, s1 = 0.f, s2 = 0.f, s3 = 0.f;
  float q0 = 0.f, q1 = 0.f, q2 = 0.f, q3 = 0.f;

  const float4* e4  = reinterpret_cast<const float4*>(e);
  const float4* hn4 = reinterpret_cast<const float4*>(hn);

  int k = slot0;
  int sc = 0, dc = 0;
  float4 ev, hs, hd;
  if (k < NE) {                       // prologue: ids + gathers for first edge
    sc = src[k]; dc = dst[k];
    ev = e4[(long long)k * 8 + lane];
    hs = hn4[(long long)sc * 8 + lane];
    hd = hn4[(long long)dc * 8 + lane];
  }
  while (k < NE) {
    const int kn = k + nslots;
    int sn = 0, dn = 0;
    if (kn < NE) { sn = src[kn]; dn = dst[kn]; }    // issue next ids (indep)
    // scatter for current edge (indep of gathers)
    if (lane == 0) {
      int pos = atomicAdd(&curs[dc], 1);
      eid2[pos] = make_int2(k, sc);
    }
    // consume current gathers (issued one iteration ago)
    float x0 = ev.x + hs.x + hd.x;
    float x1 = ev.y + hs.y + hd.y;
    float x2 = ev.z + hs.z + hd.z;
    float x3 = ev.w + hs.w + hd.w;
    s0 += x0; s1 += x1; s2 += x2; s3 += x3;
    q0 += x0 * x0; q1 += x1 * x1; q2 += x2 * x2; q3 += x3 * x3;
    // issue next gathers (ids just arrived)
    if (kn < NE) {
      ev = e4[(long long)kn * 8 + lane];
      hs = hn4[(long long)sn * 8 + lane];
      hd = hn4[(long long)dn * 8 + lane];
    }
    sc = sn; dc = dn; k = kn;
  }

  __shared__ float sh[64];
  if (threadIdx.x < 64) sh[threadIdx.x] = 0.f;
  __syncthreads();
  const int cb = lane * 4;
  atomicAdd(&sh[cb + 0], s0); atomicAdd(&sh[cb + 1], s1);
  atomicAdd(&sh[cb + 2], s2); atomicAdd(&sh[cb + 3], s3);
  atomicAdd(&sh[32 + cb + 0], q0); atomicAdd(&sh[32 + cb + 1], q1);
  atomicAdd(&sh[32 + cb + 2], q2); atomicAdd(&sh[32 + cb + 3], q3);
  __syncthreads();
  if (threadIdx.x < 64)
    atomicAdd(&stats_e[(blockIdx.x & (SCOPIES - 1)) * 64 + threadIdx.x], sh[threadIdx.x]);
}

// ---------------- finalize e-stats ----------------
__global__ void k_fin_e(const float* __restrict__ stats_e, float* __restrict__ fin) {
  int t = threadIdx.x;   // 32 threads
  float s = 0.f, q = 0.f;
  for (int c = 0; c < SCOPIES; ++c) {
    s += stats_e[c * 64 + t];
    q += stats_e[c * 64 + 32 + t];
  }
  float mean = s / (float)NE;
  float var = q / (float)NE - mean * mean;
  fin[64 + t] = mean;
  fin[96 + t] = rsqrtf(var + 1e-5f);
}

// ---- kernel E: gather-aggregate + node update + h-stats + e_out, pipelined ----
__global__ __launch_bounds__(256) void k_agg(const float* __restrict__ e,
                                             const float* __restrict__ hn,
                                             const int* __restrict__ offs,
                                             const int2* __restrict__ eid2,
                                             const float* __restrict__ norm,
                                             const float* __restrict__ fin,
                                             const float* __restrict__ ge,
                                             const float* __restrict__ be,
                                             float* __restrict__ hpre,
                                             float* __restrict__ eout,
                                             float* __restrict__ stats_h) {
  const int g = (blockIdx.x * blockDim.x + threadIdx.x) >> 3;  // node id (3125 blocks)
  const int lane = threadIdx.x & 7;
  const int cb = lane * 4;
  float n0 = 0.f, n1 = 0.f, n2 = 0.f, n3 = 0.f;
  float d0 = 0.f, d1 = 0.f, d2 = 0.f, d3 = 0.f;

  const float4* e4  = reinterpret_cast<const float4*>(e);
  const float4* hn4 = reinterpret_cast<const float4*>(hn);

  float me0 = fin[64 + cb + 0], me1 = fin[64 + cb + 1], me2 = fin[64 + cb + 2], me3 = fin[64 + cb + 3];
  float ie0 = fin[96 + cb + 0], ie1 = fin[96 + cb + 1], ie2 = fin[96 + cb + 2], ie3 = fin[96 + cb + 3];
  float ge0 = ge[cb + 0], ge1 = ge[cb + 1], ge2 = ge[cb + 2], ge3 = ge[cb + 3];
  float be0 = be[cb + 0], be1 = be[cb + 1], be2 = be[cb + 2], be3 = be[cb + 3];

  float4 hv = hn4[(long long)g * 8 + lane];

  const int lo = offs[g];
  const int hi = offs[g + 1];
  int2 kk;
  float4 ev, hs;
  if (lo < hi) {                      // prologue
    kk = eid2[lo];
    ev = e4[(long long)kk.x * 8 + lane];
    hs = hn4[(long long)kk.y * 8 + lane];
  }
  for (int p = lo; p < hi; ++p) {
    const int pn = (p + 1 < hi) ? p + 1 : p;
    int2 kn = eid2[pn];               // issue next id pair (indep)
    // consume current (gathers issued one iteration ago)
    float x0 = ev.x + hs.x + hv.x;
    float x1 = ev.y + hs.y + hv.y;
    float x2 = ev.z + hs.z + hv.z;
    float x3 = ev.w + hs.w + hv.w;
    float g0 = 1.f / (1.f + __expf(-x0));
    float g1 = 1.f / (1.f + __expf(-x1));
    float g2 = 1.f / (1.f + __expf(-x2));
    float g3 = 1.f / (1.f + __expf(-x3));
    n0 += g0 * hs.x; n1 += g1 * hs.y; n2 += g2 * hs.z; n3 += g3 * hs.w;
    d0 += g0; d1 += g1; d2 += g2; d3 += g3;
    fx4 ov;
    ov.x = fmaxf(0.f, (x0 - me0) * ie0 * ge0 + be0);
    ov.y = fmaxf(0.f, (x1 - me1) * ie1 * ge1 + be1);
    ov.z = fmaxf(0.f, (x2 - me2) * ie2 * ge2 + be2);
    ov.w = fmaxf(0.f, (x3 - me3) * ie3 * ge3 + be3);
    __builtin_nontemporal_store(ov, reinterpret_cast<fx4*>(eout) + ((long long)kk.x * 8 + lane));
    // issue next gathers
    ev = e4[(long long)kn.x * 8 + lane];
    hs = hn4[(long long)kn.y * 8 + lane];
    kk = kn;
  }

  float nm = norm[g];
  float y0 = (hv.x + n0 / (d0 + 1e-6f)) * nm;
  float y1 = (hv.y + n1 / (d1 + 1e-6f)) * nm;
  float y2 = (hv.z + n2 / (d2 + 1e-6f)) * nm;
  float y3 = (hv.w + n3 / (d3 + 1e-6f)) * nm;
  reinterpret_cast<float4*>(hpre)[(long long)g * 8 + lane] = make_float4(y0, y1, y2, y3);

  __shared__ float sh[64];
  if (threadIdx.x < 64) sh[threadIdx.x] = 0.f;
  __syncthreads();
  atomicAdd(&sh[cb + 0], y0); atomicAdd(&sh[cb + 1], y1);
  atomicAdd(&sh[cb + 2], y2); atomicAdd(&sh[cb + 3], y3);
  atomicAdd(&sh[32 + cb + 0], y0 * y0); atomicAdd(&sh[32 + cb + 1], y1 * y1);
  atomicAdd(&sh[32 + cb + 2], y2 * y2); atomicAdd(&sh[32 + cb + 3], y3 * y3);
  __syncthreads();
  if (threadIdx.x < 64)
    atomicAdd(&stats_h[(blockIdx.x & (SCOPIES - 1)) * 64 + threadIdx.x], sh[threadIdx.x]);
}

// ---------------- finalize h-stats ----------------
__global__ void k_fin_h(const float* __restrict__ stats_h, float* __restrict__ fin) {
  int t = threadIdx.x;   // 32 threads
  float s = 0.f, q = 0.f;
  for (int c = 0; c < SCOPIES; ++c) {
    s += stats_h[c * 64 + t];
    q += stats_h[c * 64 + 32 + t];
  }
  float mean = s / (float)NN;
  float var = q / (float)NN - mean * mean;
  fin[t] = mean;
  fin[32 + t] = rsqrtf(var + 1e-5f);
}

// ---------------- in-place BN + ReLU apply (h only) ----------------
__global__ __launch_bounds__(256) void k_apply(float* __restrict__ buf,
                                               long long nslots,
                                               const float* __restrict__ mean,
                                               const float* __restrict__ inv,
                                               const float* __restrict__ gamma,
                                               const float* __restrict__ beta) {
  long long i = (long long)blockIdx.x * blockDim.x + threadIdx.x;
  if (i >= nslots) return;
  const int cb = (int)(i & 7) * 4;
  float4 x = reinterpret_cast<float4*>(buf)[i];
  float y0 = fmaxf(0.f, (x.x - mean[cb + 0]) * inv[cb + 0] * gamma[cb + 0] + beta[cb + 0]);
  float y1 = fmaxf(0.f, (x.y - mean[cb + 1]) * inv[cb + 1] * gamma[cb + 1] + beta[cb + 1]);
  float y2 = fmaxf(0.f, (x.z - mean[cb + 2]) * inv[cb + 2] * gamma[cb + 2] + beta[cb + 2]);
  float y3 = fmaxf(0.f, (x.w - mean[cb + 3]) * inv[cb + 3] * gamma[cb + 3] + beta[cb + 3]);
  reinterpret_cast<float4*>(buf)[i] = make_float4(y0, y1, y2, y3);
}

extern "C" void kernel_launch(void* const* d_in, const int* in_sizes, int n_in,
                              void* d_out, int out_size, void* d_ws, size_t ws_size,
                              hipStream_t stream) {
  const float* h     = (const float*)d_in[0];
  const float* e     = (const float*)d_in[1];
  const float* norm  = (const float*)d_in[2];
  const int*   src   = (const int*)d_in[3];
  const int*   dst   = (const int*)d_in[4];
  const float* gh    = (const float*)d_in[5];
  const float* bh    = (const float*)d_in[6];
  const float* ge    = (const float*)d_in[7];
  const float* be    = (const float*)d_in[8];
  (void)in_sizes; (void)n_in; (void)out_size; (void)ws_size;

  float* ws    = (float*)d_ws;
  float* hn    = ws + OFF_HN;
  int*   deg   = (int*)(ws + OFF_DEG);
  float* se    = ws + OFF_SE;
  float* shh   = ws + OFF_SH;
  float* fin   = ws + OFF_FIN;
  int*   offs  = (int*)(ws + OFF_OFFS);
  int*   curs  = (int*)(ws + OFF_CURS);
  int*   texcl = (int*)(ws + OFF_TEX);
  int*   parts = (int*)(ws + OFF_PART);
  int2*  eid2  = (int2*)(ws + OFF_EID2);

  float* out  = (float*)d_out;
  float* hpre = out;                           // [NN*32] h output region
  float* eout = out + (long long)NN * DIMS;    // [NE*32] e output region

  // zero deg + stats (contiguous: OFF_DEG .. OFF_FIN)
  (void)hipMemsetAsync(deg, 0, (size_t)(OFF_FIN - OFF_DEG) * sizeof(float), stream);

  k_hn<<<(NN * 8 + 255) / 256, 256, 0, stream>>>(h, norm, hn);
  k_hist<<<(NE / 4 + 255) / 256, 256, 0, stream>>>(dst, deg);
  k_scanA<<<SCAN_NB, SCAN_NTH, 0, stream>>>(deg, texcl, parts);
  k_scanB<<<1, SCAN_NB, 0, stream>>>(parts);
  k_scanC<<<SCAN_NB, SCAN_NTH, 0, stream>>>(deg, texcl, parts, offs, curs);
  k_edge<<<2048, 256, 0, stream>>>(e, hn, src, dst, curs, eid2, se);
  k_fin_e<<<1, 32, 0, stream>>>(se, fin);
  k_agg<<<NN * 8 / 256, 256, 0, stream>>>(e, hn, offs, eid2, norm, fin, ge, be,
                                          hpre, eout, shh);
  k_fin_h<<<1, 32, 0, stream>>>(shh, fin);
  k_apply<<<(NN * 8 + 255) / 256, 256, 0, stream>>>(hpre, (long long)NN * 8,
                                                    fin + 0, fin + 32, gh, bh);
}